// Round 19
// baseline (680.485 us; speedup 1.0000x reference)
//
#include <hip/hip_runtime.h>
#include <hip/hip_bf16.h>
#include <math.h>

// Problem constants: B=4, T=512, I=128, H=128 (4H=512)
#define Bq 4
#define Tq 512
#define Hq 128

typedef _Float16 f16x4 __attribute__((ext_vector_type(4)));
typedef _Float16 f16x8 __attribute__((ext_vector_type(8)));
typedef float f32x4 __attribute__((ext_vector_type(4)));

__device__ __forceinline__ float rcp_fast(float x) { return __builtin_amdgcn_rcpf(x); }
__device__ __forceinline__ float sigmoid_fast(float x) {
    return rcp_fast(1.0f + __expf(-x));
}
__device__ __forceinline__ float tanh_fast(float x) {
    float e = __expf(2.0f * x);
    return 1.0f - 2.0f * rcp_fast(e + 1.0f);
}

// ---------------------------------------------------------------------------
// GEMM-nt body, 256 threads: C[m,n] = sum_k A[m,k]*W[n,k] (+bias)(+=C), K=128.
// ---------------------------------------------------------------------------
__device__ __forceinline__ void gemm_nt_body(float (*As)[68], float (*Ws)[68],
                                             const float* __restrict__ A, int lda,
                                             const float* __restrict__ W, int ldw,
                                             const float* __restrict__ bias,
                                             float* __restrict__ C, int acc_flag,
                                             int m0, int n0, int tid) {
    int tx = tid & 15, ty = tid >> 4;
    float acc[4][4] = {};
    for (int kc = 0; kc < 2; kc++) {
        __syncthreads();
#pragma unroll
        for (int i = 0; i < 4; i++) {
            int idx = tid + 256 * i;
            int r = idx >> 4, c4 = idx & 15;
            *(float4*)(&As[r][c4 * 4]) = *(const float4*)(A + (size_t)(m0 + r) * lda + kc * 64 + c4 * 4);
            *(float4*)(&Ws[r][c4 * 4]) = *(const float4*)(W + (size_t)(n0 + r) * ldw + kc * 64 + c4 * 4);
        }
        __syncthreads();
#pragma unroll
        for (int k4 = 0; k4 < 16; k4++) {
            float4 a[4], wv[4];
#pragma unroll
            for (int i = 0; i < 4; i++) a[i] = *(const float4*)(&As[ty * 4 + i][k4 * 4]);
#pragma unroll
            for (int j = 0; j < 4; j++) wv[j] = *(const float4*)(&Ws[tx * 4 + j][k4 * 4]);
#pragma unroll
            for (int i = 0; i < 4; i++)
#pragma unroll
                for (int j = 0; j < 4; j++)
                    acc[i][j] += a[i].x * wv[j].x + a[i].y * wv[j].y + a[i].z * wv[j].z + a[i].w * wv[j].w;
        }
    }
#pragma unroll
    for (int i = 0; i < 4; i++) {
        int m = m0 + ty * 4 + i;
        int n = n0 + tx * 4;
        float4 v = make_float4(acc[i][0], acc[i][1], acc[i][2], acc[i][3]);
        if (bias) { v.x += bias[n]; v.y += bias[n + 1]; v.z += bias[n + 2]; v.w += bias[n + 3]; }
        if (acc_flag) {
            float4 o = *(const float4*)(C + (size_t)m * 512 + n);
            v.x += o.x; v.y += o.y; v.z += o.z; v.w += o.w;
        }
        *(float4*)(C + (size_t)m * 512 + n) = v;
    }
}

// ---------------------------------------------------------------------------
// GEMM-nt body, 1024 threads (lstm-shadow side blocks). Tile 64x64, K=128.
// Thread: row ty=tid>>4 (0..63), cols tx*4 (tx=tid&15). 1 float4 load/matrix.
// ---------------------------------------------------------------------------
__device__ __forceinline__ void gemm_nt_1024(float (*As)[68], float (*Ws)[68],
                                             const float* __restrict__ A, int lda,
                                             const float* __restrict__ W, int ldw,
                                             const float* __restrict__ bias,
                                             float* __restrict__ C,
                                             int m0, int n0, int tid) {
    int tx = tid & 15, ty = tid >> 4;   // ty 0..63
    float acc[4] = {};
    for (int kc = 0; kc < 2; kc++) {
        __syncthreads();
        {
            int r = tid >> 4, c4 = tid & 15;
            *(float4*)(&As[r][c4 * 4]) = *(const float4*)(A + (size_t)(m0 + r) * lda + kc * 64 + c4 * 4);
            *(float4*)(&Ws[r][c4 * 4]) = *(const float4*)(W + (size_t)(n0 + r) * ldw + kc * 64 + c4 * 4);
        }
        __syncthreads();
#pragma unroll
        for (int k4 = 0; k4 < 16; k4++) {
            float4 a = *(const float4*)(&As[ty][k4 * 4]);
#pragma unroll
            for (int j = 0; j < 4; j++) {
                float4 wv = *(const float4*)(&Ws[tx * 4 + j][k4 * 4]);
                acc[j] += a.x * wv.x + a.y * wv.y + a.z * wv.z + a.w * wv.w;
            }
        }
    }
    int m = m0 + ty;
    int n = n0 + tx * 4;
    float4 v = make_float4(acc[0], acc[1], acc[2], acc[3]);
    if (bias) { v.x += bias[n]; v.y += bias[n + 1]; v.z += bias[n + 2]; v.w += bias[n + 3]; }
    *(float4*)(C + (size_t)m * 512 + n) = v;
}

// ---------------------------------------------------------------------------
// prep: xg_s projection (256 tiles) + W16_s convert (64 blocks). grid 320.
// ---------------------------------------------------------------------------
__global__ __launch_bounds__(256) void prep(const float* __restrict__ x,
                                            const float* __restrict__ Wih_s,
                                            const float* __restrict__ b_s,
                                            const float* __restrict__ Whh_s,
                                            float* __restrict__ xg_s,
                                            _Float16* __restrict__ W16_s) {
    __shared__ __align__(16) float As[64][68];
    __shared__ __align__(16) float Ws[64][68];
    int bid = blockIdx.x;
    int tid = threadIdx.x;
    if (bid < 256) {
        gemm_nt_body(As, Ws, x, 128, Wih_s, 128, b_s, xg_s, 0,
                     (bid & 31) * 64, (bid >> 5) * 64, tid);
    } else {
        int cb = bid - 256;                      // 0..63
        int i = (cb * 256 + tid) * 4;
        float4 v = *(const float4*)(Whh_s + i);
        f16x4 o;
        o[0] = (_Float16)v.x; o[1] = (_Float16)v.y;
        o[2] = (_Float16)v.z; o[3] = (_Float16)v.w;
        *(f16x4*)(W16_s + i) = o;
    }
}

// ---------------------------------------------------------------------------
// gemm_nt standalone (R-projection accumulate). grid (32,8), block 256.
// ---------------------------------------------------------------------------
__global__ __launch_bounds__(256) void gemm_nt(const float* __restrict__ A, int lda,
                                               const float* __restrict__ W, int ldw,
                                               const float* __restrict__ bias,
                                               float* __restrict__ C, int acc_flag) {
    __shared__ __align__(16) float As[64][68];
    __shared__ __align__(16) float Ws[64][68];
    gemm_nt_body(As, Ws, A, lda, W, ldw, bias, C, acc_flag,
                 blockIdx.x * 64, blockIdx.y * 64, threadIdx.x);
}

// ---------------------------------------------------------------------------
// mid: both attention-precursor GEMMs in one launch. flat grid 128.
//  cfg0: hp_t = Hsh@Wht (row-major)
//  cfg1: tc_sT = tanh(x@Wx + Hsh@Whs + bs)^T to [b][h][s]
// ---------------------------------------------------------------------------
__global__ __launch_bounds__(256) void mid(const float* __restrict__ x,
                                           const float* __restrict__ Hsh,
                                           const float* __restrict__ Wht,
                                           const float* __restrict__ Wx,
                                           const float* __restrict__ Whs,
                                           const float* __restrict__ bs,
                                           float* __restrict__ hp_t,
                                           float* __restrict__ tc_sT) {
    __shared__ __align__(16) float As[64][68];
    __shared__ __align__(16) float Bs[64][68];
    int bid = blockIdx.x;
    int cfg = bid >> 6;          // 0: hp_t, 1: tc_sT
    int b2 = bid & 63;
    int m0 = (b2 & 31) * 64, n0 = (b2 >> 5) * 64;
    const float* A1 = cfg ? x : Hsh;
    const float* B1 = cfg ? Wx : Wht;
    const float* A2 = cfg ? Hsh : nullptr;
    const float* B2 = cfg ? Whs : nullptr;

    int tid = threadIdx.x;
    int tx = tid & 15, ty = tid >> 4;
    float acc[4][4] = {};
    for (int src = 0; src < 2; src++) {
        const float* A = src ? A2 : A1;
        const float* Bm = src ? B2 : B1;
        if (!A) break;
        for (int kc = 0; kc < 2; kc++) {
            __syncthreads();
#pragma unroll
            for (int i = 0; i < 4; i++) {
                int idx = tid + 256 * i;
                int r = idx >> 4, c4 = idx & 15;
                *(float4*)(&As[r][c4 * 4]) = *(const float4*)(A + (size_t)(m0 + r) * 128 + kc * 64 + c4 * 4);
                *(float4*)(&Bs[r][c4 * 4]) = *(const float4*)(Bm + (size_t)(kc * 64 + r) * 128 + n0 + c4 * 4);
            }
            __syncthreads();
#pragma unroll
            for (int k4 = 0; k4 < 16; k4++) {
                float4 a[4];
#pragma unroll
                for (int i = 0; i < 4; i++) a[i] = *(const float4*)(&As[ty * 4 + i][k4 * 4]);
#pragma unroll
                for (int kk = 0; kk < 4; kk++) {
                    float4 bv = *(const float4*)(&Bs[k4 * 4 + kk][tx * 4]);
#pragma unroll
                    for (int i = 0; i < 4; i++) {
                        float av = (kk == 0) ? a[i].x : (kk == 1) ? a[i].y : (kk == 2) ? a[i].z : a[i].w;
                        acc[i][0] += av * bv.x;
                        acc[i][1] += av * bv.y;
                        acc[i][2] += av * bv.z;
                        acc[i][3] += av * bv.w;
                    }
                }
            }
        }
    }
    if (cfg == 0) {
#pragma unroll
        for (int i = 0; i < 4; i++) {
            int m = m0 + ty * 4 + i;
            int n = n0 + tx * 4;
            *(float4*)(hp_t + (size_t)m * 128 + n) =
                make_float4(acc[i][0], acc[i][1], acc[i][2], acc[i][3]);
        }
    } else {
        __syncthreads();
#pragma unroll
        for (int i = 0; i < 4; i++)
#pragma unroll
            for (int j = 0; j < 4; j++)
                As[ty * 4 + i][tx * 4 + j] = tanh_fast(acc[i][j] + bs[n0 + tx * 4 + j]);
        __syncthreads();
        int b = m0 >> 9;
        int s0 = m0 & 511;
        int lane = tid & 63, wv = tid >> 6;
#pragma unroll 4
        for (int it = 0; it < 16; ++it) {
            int nl = wv * 16 + it;
            tc_sT[((size_t)(b * 128 + n0 + nl)) * 512 + s0 + lane] = As[lane][nl];
        }
    }
}

// ---------------------------------------------------------------------------
// LSTM core v2: 16-wave GATE-SPLIT. 1024 threads (4 waves/SIMD, 2x TLP).
// Wave (w8 = wid&7, gp = wid>>3): gp=0 computes gates i,f; gp=1 gates g,o,
// for channels 16*w8 + r (r=lane&15, kg=lane>>4 = batch). Each wave: 8 MFMA
// (2 gates x 4 kb, full K), B-frags 8 f16x8 in AGPRs (volatile-pinned).
// Exchange: gp1 writes (tanh(g), sigm(o)) float2 to LDS; gp0 computed
// sigm(i),sigm(f) in parallel, then after barrier does c/h update + writes.
// Two lean lgkm-only barriers/step. Serial trans chain split across waves;
// 4 waves/SIMD overlap ds_read/gate/barrier stalls (R18: 2 waves, 1130cyc/
// step vs 620 MFMA-issue floor).
// ---------------------------------------------------------------------------
#define MF0(ACC, A, B) \
    asm("v_mfma_f32_16x16x32_f16 %0, %1, %2, %3" : "=&v"(ACC) : "v"(A), "a"(B), "v"(zro));
#define MF(ACC, A, B) \
    asm("v_mfma_f32_16x16x32_f16 %0, %1, %2, %0" : "+v"(ACC) : "v"(A), "a"(B));

#define LSTM_STEP(X0, X1, R0, R1, R2, R3, WPTR, PXG)                               \
    {                                                                              \
        f16x8 a0 = *(R0); f16x8 a1 = *(R1);                                        \
        f16x8 a2 = *(R2); f16x8 a3 = *(R3);                                        \
        float o0 = X0, o1 = X1;                                                    \
        X0 = (PXG)[0]; X1 = (PXG)[128];                                            \
        (PXG) += 1024;                                                             \
        f32x4 ac0a, ac0b, ac1a, ac1b;                                              \
        MF0(ac0a, a0, bg00) MF0(ac1a, a0, bg10)                                    \
        MF0(ac0b, a2, bg02) MF0(ac1b, a2, bg12)                                    \
        MF(ac0a, a1, bg01) MF(ac1a, a1, bg11)                                      \
        MF(ac0b, a3, bg03) MF(ac1b, a3, bg13)                                      \
        __builtin_amdgcn_sched_barrier(0);                                         \
        asm volatile("s_nop 7\n\ts_nop 7"                                          \
                     :: "v"(ac0a), "v"(ac0b), "v"(ac1a), "v"(ac1b));               \
        __builtin_amdgcn_sched_barrier(0);                                         \
        float g0 = ac0a[0] + ac0b[0] + o0;                                         \
        float g1 = ac1a[0] + ac1b[0] + o1;                                         \
        float si = 0.f, sf = 0.f;                                                  \
        if (gp) {                                                                  \
            float tg = tanh_fast(g0);                                              \
            float so = sigmoid_fast(g1);                                           \
            exch[exidx] = make_float2(tg, so);                                     \
        } else {                                                                   \
            si = sigmoid_fast(g0);                                                 \
            sf = sigmoid_fast(g1);                                                 \
        }                                                                          \
        __builtin_amdgcn_sched_barrier(0);                                         \
        asm volatile("s_waitcnt lgkmcnt(0)");                                      \
        __builtin_amdgcn_s_barrier();                                              \
        __builtin_amdgcn_sched_barrier(0);                                         \
        if (!gp) {                                                                 \
            float2 e = exch[exidx];                                                \
            c = sf * c + si * e.x;                                                 \
            float h = e.y * tanh_fast(c);                                          \
            *(WPTR) = (_Float16)h;                                                 \
            *pH = h; pH += Hq;                                                     \
        }                                                                          \
        __builtin_amdgcn_sched_barrier(0);                                         \
        asm volatile("s_waitcnt lgkmcnt(0)");                                      \
        __builtin_amdgcn_s_barrier();                                              \
        __builtin_amdgcn_sched_barrier(0);                                         \
    }

__device__ __forceinline__ void lstm_core(const float* __restrict__ xg,
                                          const _Float16* __restrict__ W16,
                                          float* __restrict__ Hout,
                                          _Float16* hbase, float2* exch, int tid) {
    int wid = tid >> 6, lane = tid & 63;
    int w8 = wid & 7, gp = wid >> 3;     // gp: 0 -> gates i,f ; 1 -> gates g,o
    int r = lane & 15, kg = lane >> 4;   // kg = k-group AND batch id
    int ch = 16 * w8 + r;
    int exidx = w8 * 64 + lane;

    for (int i = tid; i < 4096; i += 1024) hbase[i] = (_Float16)0.f;

    // B-frags for this wave's 2 gates (g0 = 2*gp, g1 = 2*gp+1), 4 kb each
    const _Float16* wb = W16 + (size_t)((2 * gp) * 128 + ch) * 128 + kg * 8;
#define LWB(g, kb) *(const f16x8*)(wb + (size_t)(g) * 16384 + (kb) * 32)
    f16x8 bg00 = LWB(0, 0), bg01 = LWB(0, 1), bg02 = LWB(0, 2), bg03 = LWB(0, 3);
    f16x8 bg10 = LWB(1, 0), bg11 = LWB(1, 1), bg12 = LWB(1, 2), bg13 = LWB(1, 3);
#undef LWB
    f32x4 zro = {0.f, 0.f, 0.f, 0.f};
    asm volatile(""
                 : "+a"(bg00), "+a"(bg01), "+a"(bg02), "+a"(bg03),
                   "+a"(bg10), "+a"(bg11), "+a"(bg12), "+a"(bg13),
                   "+v"(zro));

    int aoff0 = r * 128 + (((0 * 4 + kg) ^ r) << 3);
    int aoff1 = r * 128 + (((1 * 4 + kg) ^ r) << 3);
    int aoff2 = r * 128 + (((2 * 4 + kg) ^ r) << 3);
    int aoff3 = r * 128 + (((3 * 4 + kg) ^ r) << 3);
    int woff = (4 * kg) * 128 + (((ch >> 3) ^ (4 * kg)) << 3) + (ch & 7);

    const f16x8* rA0 = (const f16x8*)(hbase + aoff0);
    const f16x8* rA1 = (const f16x8*)(hbase + aoff1);
    const f16x8* rA2 = (const f16x8*)(hbase + aoff2);
    const f16x8* rA3 = (const f16x8*)(hbase + aoff3);
    const f16x8* rB0 = (const f16x8*)(hbase + 2048 + aoff0);
    const f16x8* rB1 = (const f16x8*)(hbase + 2048 + aoff1);
    const f16x8* rB2 = (const f16x8*)(hbase + 2048 + aoff2);
    const f16x8* rB3 = (const f16x8*)(hbase + 2048 + aoff3);
    _Float16* wA = hbase + 2048 + woff;
    _Float16* wB = hbase + woff;

    size_t kgTq = (size_t)kg * Tq;
    // xg offsets: gp=0 reads gates 0,1 (i,f); gp=1 reads gates 2,3 (g,o)
    const float* p0 = xg + (kgTq + 0) * 512 + gp * 256 + ch;
    const float* p1 = xg + (kgTq + 1) * 512 + gp * 256 + ch;
    float xa0 = p0[0], xa1 = p0[128];
    float xb0 = p1[0], xb1 = p1[128];
    const float* pA = xg + (kgTq + 2) * 512 + gp * 256 + ch;
    const float* pB = xg + (kgTq + 3) * 512 + gp * 256 + ch;
    float* pH = Hout + kgTq * Hq + ch;

    float c = 0.f;
    __syncthreads();

    for (int t = 0; t < Tq; t += 2) {
        LSTM_STEP(xa0, xa1, rA0, rA1, rA2, rA3, wA, pA)
        LSTM_STEP(xb0, xb1, rB0, rB1, rB2, rB3, wB, pB)
    }
}

// ---------------------------------------------------------------------------
// lstm_fused: block 0 = shared-LSTM recurrence (16 waves); blocks 1..256
// xg_t projection; blocks 257..320 Whh_t->f16 convert (shadow work).
// ---------------------------------------------------------------------------
__global__ __launch_bounds__(1024)
void lstm_fused(const float* __restrict__ xg_s,
                const _Float16* __restrict__ W16_s,
                float* __restrict__ Hsh,
                const float* __restrict__ x,
                const float* __restrict__ Wih_t,
                const float* __restrict__ b_t,
                const float* __restrict__ Whh_t,
                float* __restrict__ xg_t,
                _Float16* __restrict__ W16_t) {
    __shared__ __align__(16) float smem[2][64][68];
    int bid = blockIdx.x;
    int tid = threadIdx.x;
    if (bid == 0) {
        lstm_core(xg_s, W16_s, Hsh, (_Float16*)&smem[0][0][0],
                  (float2*)((char*)&smem[0][0][0] + 8192), tid);
    } else if (bid <= 256) {
        int b2 = bid - 1;
        gemm_nt_1024(smem[0], smem[1], x, 128, Wih_t, 256, b_t, xg_t,
                     (b2 & 31) * 64, (b2 >> 5) * 64, tid);
    } else {
        int cb = bid - 257;                      // 0..63
        int i = cb * 1024 + tid;
        W16_t[i] = (_Float16)Whh_t[i];
    }
}

// ---------------------------------------------------------------------------
// lstm_b4 plain (task LSTM). grid 1, block 1024.
// ---------------------------------------------------------------------------
__global__ __launch_bounds__(1024)
void lstm_b4(const float* __restrict__ xg,
             const _Float16* __restrict__ W16,
             float* __restrict__ Hout) {
    __shared__ __align__(16) _Float16 hbuf[4096];
    __shared__ __align__(16) float2 exch[512];
    lstm_core(xg, W16, Hout, hbuf, exch, threadIdx.x);
}

// ---------------------------------------------------------------------------
// Attention v8 (R18-proven): exact tanh addition identity, 1 rcp/elem.
// 4 t's per block, 512 blocks x 512 thr.
// ---------------------------------------------------------------------------
__global__ __launch_bounds__(512) void attn_kernel(const float* __restrict__ hp_t,
                                                   const float* __restrict__ tc_sT,
                                                   const float* __restrict__ u,
                                                   const float* __restrict__ Hsh,
                                                   float* __restrict__ R) {
    int t0 = blockIdx.x * 4;
    int b = blockIdx.y;
    int tid = threadIdx.x;
    int tq = tid >> 7, th = tid & 127;

    __shared__ __align__(16) float pa_lds[4][128];
    __shared__ __align__(16) float u_lds[128];
    __shared__ __align__(16) float sc[4][512];
    __shared__ __align__(16) float red[8];

    pa_lds[tq][th] = tanh_fast(hp_t[((size_t)b * Tq + t0 + tq) * Hq + th]);
    if (tid < 128) u_lds[tid] = u[tid];
    __syncthreads();

    const float* pc = tc_sT + (size_t)b * 65536 + 4 * th;   // [b][h][s]
    const float* pa = &pa_lds[tq][0];
    float acc0 = 0.f, acc1 = 0.f, acc2 = 0.f, acc3 = 0.f;
#pragma unroll 4
    for (int h = 0; h < 128; ++h) {
        float4 qv = *(const float4*)pc;
        float p = pa[h], uu = u_lds[h];
        float n0 = p + qv.x, n1 = p + qv.y, n2 = p + qv.z, n3 = p + qv.w;
        float d0 = fmaf(p, qv.x, 1.0f), d1 = fmaf(p, qv.y, 1.0f);
        float d2 = fmaf(p, qv.z, 1.0f), d3 = fmaf(p, qv.w, 1.0f);
        acc0 = fmaf(uu * n0, rcp_fast(d0), acc0);
        acc1 = fmaf(uu * n1, rcp_fast(d1), acc1);
        acc2 = fmaf(uu * n2, rcp_fast(d2), acc2);
        acc3 = fmaf(uu * n3, rcp_fast(d3), acc3);
        pc += 512;
    }
    float p0 = __expf(acc0), p1 = __expf(acc1);
    float p2 = __expf(acc2), p3 = __expf(acc3);
    *(float4*)&sc[tq][4 * th] = make_float4(p0, p1, p2, p3);

    float psum = p0 + p1 + p2 + p3;
#pragma unroll
    for (int off = 1; off < 64; off <<= 1) psum += __shfl_xor(psum, off, 64);
    int wv = tid >> 6;
    if ((tid & 63) == 0) red[wv] = psum;
    __syncthreads();
    float rinv = rcp_fast(red[2 * tq] + red[2 * tq + 1]);

    const float* hb = Hsh + (size_t)b * Tq * Hq + th;
    const float* scp = &sc[tq][0];
    float acc = 0.0f;
#pragma unroll 4
    for (int s = 0; s < 512; ++s) {
        acc = fmaf(scp[s], hb[(size_t)s * Hq], acc);
    }
    R[((size_t)b * Tq + t0 + tq) * Hq + th] = acc * rinv;
}

// ---------------------------------------------------------------------------
extern "C" void kernel_launch(void* const* d_in, const int* in_sizes, int n_in,
                              void* d_out, int out_size, void* d_ws, size_t ws_size,
                              hipStream_t stream) {
    const float* x      = (const float*)d_in[0];
    const float* Wih_s  = (const float*)d_in[1];
    const float* Whh_s  = (const float*)d_in[2];
    const float* b_s    = (const float*)d_in[3];
    const float* Wx     = (const float*)d_in[4];
    const float* Wht    = (const float*)d_in[5];
    const float* Whs    = (const float*)d_in[6];
    const float* bs     = (const float*)d_in[7];
    const float* u      = (const float*)d_in[8];
    // d_in[9] = bu: softmax-invariant, unused
    const float* Wih_t  = (const float*)d_in[10];
    const float* Whh_t  = (const float*)d_in[11];
    const float* b_t    = (const float*)d_in[12];
    float* out = (float*)d_out;

    // workspace layout (floats)
    float* ws    = (float*)d_ws;
    float* xg_s  = ws;                 // [B,T,512]
    float* xg_t  = ws + 1048576;       // [B,T,512]
    float* Hsh   = ws + 2097152;       // [B,T,128]
    float* hp_t  = ws + 2359296;       // [B,T,128] (W16_s home until mid writes)
    float* tc_sT = ws + 2621440;       // [B,128,512] tanh'd + transposed
    float* Rbuf  = ws + 2883584;       // [B,T,128]
    _Float16* W16_t = (_Float16*)(ws + 3145728);   // tail, survives to lstm2
    _Float16* W16_s = (_Float16*)hp_t;             // consumed by lstm1 before mid

    dim3 blk(256);

    // 1) prep: xg_s projection + W16_s convert (critical path to lstm1)
    prep<<<320, blk, 0, stream>>>(x, Wih_s, b_s, Whh_s, xg_s, W16_s);

    // 2) shared LSTM (block 0, 16-wave gate-split) + shadow work
    lstm_fused<<<321, 1024, 0, stream>>>(xg_s, W16_s, Hsh,
                                         x, Wih_t, b_t, Whh_t, xg_t, W16_t);

    // 3) attention precursors: hp_t ; tc_sT = tanh(c_s)^T
    mid<<<128, blk, 0, stream>>>(x, Hsh, Wht, Wx, Whs, bs, hp_t, tc_sT);

    // 4) attention v8 (tanh addition identity)
    attn_kernel<<<dim3(Tq / 4, Bq), 512, 0, stream>>>(hp_t, tc_sT, u, Hsh, Rbuf);

    // 5) xg_t += R @ Wih_t[:,128:].T
    gemm_nt<<<dim3(32, 8), blk, 0, stream>>>(Rbuf, 128, Wih_t + 128, 256, nullptr, xg_t, 1);

    // 6) task LSTM -> output (16-wave gate-split)
    lstm_b4<<<1, 1024, 0, stream>>>(xg_t, W16_t, out);
}

// Round 20
// 576.269 us; speedup vs baseline: 1.1808x; 1.1808x over previous
//
#include <hip/hip_runtime.h>
#include <hip/hip_bf16.h>
#include <math.h>

// Problem constants: B=4, T=512, I=128, H=128 (4H=512)
#define Bq 4
#define Tq 512
#define Hq 128

typedef _Float16 f16x4 __attribute__((ext_vector_type(4)));
typedef _Float16 f16x8 __attribute__((ext_vector_type(8)));
typedef float f32x4 __attribute__((ext_vector_type(4)));

__device__ __forceinline__ float rcp_fast(float x) { return __builtin_amdgcn_rcpf(x); }
__device__ __forceinline__ float sigmoid_fast(float x) {
    return rcp_fast(1.0f + __expf(-x));
}
__device__ __forceinline__ float tanh_fast(float x) {
    float e = __expf(2.0f * x);
    return 1.0f - 2.0f * rcp_fast(e + 1.0f);
}

// ---------------------------------------------------------------------------
// GEMM-nt body, 256 threads: C[m,n] = sum_k A[m,k]*W[n,k] (+bias)(+=C), K=128.
// ---------------------------------------------------------------------------
__device__ __forceinline__ void gemm_nt_body(float (*As)[68], float (*Ws)[68],
                                             const float* __restrict__ A, int lda,
                                             const float* __restrict__ W, int ldw,
                                             const float* __restrict__ bias,
                                             float* __restrict__ C, int acc_flag,
                                             int m0, int n0, int tid) {
    int tx = tid & 15, ty = tid >> 4;
    float acc[4][4] = {};
    for (int kc = 0; kc < 2; kc++) {
        __syncthreads();
#pragma unroll
        for (int i = 0; i < 4; i++) {
            int idx = tid + 256 * i;
            int r = idx >> 4, c4 = idx & 15;
            *(float4*)(&As[r][c4 * 4]) = *(const float4*)(A + (size_t)(m0 + r) * lda + kc * 64 + c4 * 4);
            *(float4*)(&Ws[r][c4 * 4]) = *(const float4*)(W + (size_t)(n0 + r) * ldw + kc * 64 + c4 * 4);
        }
        __syncthreads();
#pragma unroll
        for (int k4 = 0; k4 < 16; k4++) {
            float4 a[4], wv[4];
#pragma unroll
            for (int i = 0; i < 4; i++) a[i] = *(const float4*)(&As[ty * 4 + i][k4 * 4]);
#pragma unroll
            for (int j = 0; j < 4; j++) wv[j] = *(const float4*)(&Ws[tx * 4 + j][k4 * 4]);
#pragma unroll
            for (int i = 0; i < 4; i++)
#pragma unroll
                for (int j = 0; j < 4; j++)
                    acc[i][j] += a[i].x * wv[j].x + a[i].y * wv[j].y + a[i].z * wv[j].z + a[i].w * wv[j].w;
        }
    }
#pragma unroll
    for (int i = 0; i < 4; i++) {
        int m = m0 + ty * 4 + i;
        int n = n0 + tx * 4;
        float4 v = make_float4(acc[i][0], acc[i][1], acc[i][2], acc[i][3]);
        if (bias) { v.x += bias[n]; v.y += bias[n + 1]; v.z += bias[n + 2]; v.w += bias[n + 3]; }
        if (acc_flag) {
            float4 o = *(const float4*)(C + (size_t)m * 512 + n);
            v.x += o.x; v.y += o.y; v.z += o.z; v.w += o.w;
        }
        *(float4*)(C + (size_t)m * 512 + n) = v;
    }
}

// ---------------------------------------------------------------------------
// GEMM-nt body, 512 threads (lstm-shadow side blocks). Tile 64x64, K=128.
// ---------------------------------------------------------------------------
__device__ __forceinline__ void gemm_nt_512(float (*As)[68], float (*Ws)[68],
                                            const float* __restrict__ A, int lda,
                                            const float* __restrict__ W, int ldw,
                                            const float* __restrict__ bias,
                                            float* __restrict__ C,
                                            int m0, int n0, int tid) {
    int tx = tid & 15, ty = tid >> 4;   // ty 0..31
    float acc[2][4] = {};
    for (int kc = 0; kc < 2; kc++) {
        __syncthreads();
#pragma unroll
        for (int i = 0; i < 2; i++) {
            int idx = tid + 512 * i;            // 0..1023
            int r = idx >> 4, c4 = idx & 15;
            *(float4*)(&As[r][c4 * 4]) = *(const float4*)(A + (size_t)(m0 + r) * lda + kc * 64 + c4 * 4);
            *(float4*)(&Ws[r][c4 * 4]) = *(const float4*)(W + (size_t)(n0 + r) * ldw + kc * 64 + c4 * 4);
        }
        __syncthreads();
#pragma unroll
        for (int k4 = 0; k4 < 16; k4++) {
            float4 a[2], wv[4];
#pragma unroll
            for (int i = 0; i < 2; i++) a[i] = *(const float4*)(&As[ty * 2 + i][k4 * 4]);
#pragma unroll
            for (int j = 0; j < 4; j++) wv[j] = *(const float4*)(&Ws[tx * 4 + j][k4 * 4]);
#pragma unroll
            for (int i = 0; i < 2; i++)
#pragma unroll
                for (int j = 0; j < 4; j++)
                    acc[i][j] += a[i].x * wv[j].x + a[i].y * wv[j].y + a[i].z * wv[j].z + a[i].w * wv[j].w;
        }
    }
#pragma unroll
    for (int i = 0; i < 2; i++) {
        int m = m0 + ty * 2 + i;
        int n = n0 + tx * 4;
        float4 v = make_float4(acc[i][0], acc[i][1], acc[i][2], acc[i][3]);
        if (bias) { v.x += bias[n]; v.y += bias[n + 1]; v.z += bias[n + 2]; v.w += bias[n + 3]; }
        *(float4*)(C + (size_t)m * 512 + n) = v;
    }
}

// ---------------------------------------------------------------------------
// prep: xg_s projection (256 tiles) + W16_s convert (64 blocks). grid 320.
// ---------------------------------------------------------------------------
__global__ __launch_bounds__(256) void prep(const float* __restrict__ x,
                                            const float* __restrict__ Wih_s,
                                            const float* __restrict__ b_s,
                                            const float* __restrict__ Whh_s,
                                            float* __restrict__ xg_s,
                                            _Float16* __restrict__ W16_s) {
    __shared__ __align__(16) float As[64][68];
    __shared__ __align__(16) float Ws[64][68];
    int bid = blockIdx.x;
    int tid = threadIdx.x;
    if (bid < 256) {
        gemm_nt_body(As, Ws, x, 128, Wih_s, 128, b_s, xg_s, 0,
                     (bid & 31) * 64, (bid >> 5) * 64, tid);
    } else {
        int cb = bid - 256;                      // 0..63
        int i = (cb * 256 + tid) * 4;
        float4 v = *(const float4*)(Whh_s + i);
        f16x4 o;
        o[0] = (_Float16)v.x; o[1] = (_Float16)v.y;
        o[2] = (_Float16)v.z; o[3] = (_Float16)v.w;
        *(f16x4*)(W16_s + i) = o;
    }
}

// ---------------------------------------------------------------------------
// gemm_nt standalone (R-projection accumulate). grid (32,8), block 256.
// ---------------------------------------------------------------------------
__global__ __launch_bounds__(256) void gemm_nt(const float* __restrict__ A, int lda,
                                               const float* __restrict__ W, int ldw,
                                               const float* __restrict__ bias,
                                               float* __restrict__ C, int acc_flag) {
    __shared__ __align__(16) float As[64][68];
    __shared__ __align__(16) float Ws[64][68];
    gemm_nt_body(As, Ws, A, lda, W, ldw, bias, C, acc_flag,
                 blockIdx.x * 64, blockIdx.y * 64, threadIdx.x);
}

// ---------------------------------------------------------------------------
// mid: both attention-precursor GEMMs in one launch. flat grid 128.
//  cfg0: hp_t = Hsh@Wht (row-major)
//  cfg1: tc_sT = tanh(x@Wx + Hsh@Whs + bs) TRANSPOSED to [b][h][s]
// ---------------------------------------------------------------------------
__global__ __launch_bounds__(256) void mid(const float* __restrict__ x,
                                           const float* __restrict__ Hsh,
                                           const float* __restrict__ Wht,
                                           const float* __restrict__ Wx,
                                           const float* __restrict__ Whs,
                                           const float* __restrict__ bs,
                                           float* __restrict__ hp_t,
                                           float* __restrict__ tc_sT) {
    __shared__ __align__(16) float As[64][68];
    __shared__ __align__(16) float Bs[64][68];
    int bid = blockIdx.x;
    int cfg = bid >> 6;          // 0: hp_t, 1: tc_sT
    int b2 = bid & 63;
    int m0 = (b2 & 31) * 64, n0 = (b2 >> 5) * 64;
    const float* A1 = cfg ? x : Hsh;
    const float* B1 = cfg ? Wx : Wht;
    const float* A2 = cfg ? Hsh : nullptr;
    const float* B2 = cfg ? Whs : nullptr;

    int tid = threadIdx.x;
    int tx = tid & 15, ty = tid >> 4;
    float acc[4][4] = {};
    for (int src = 0; src < 2; src++) {
        const float* A = src ? A2 : A1;
        const float* Bm = src ? B2 : B1;
        if (!A) break;
        for (int kc = 0; kc < 2; kc++) {
            __syncthreads();
#pragma unroll
            for (int i = 0; i < 4; i++) {
                int idx = tid + 256 * i;
                int r = idx >> 4, c4 = idx & 15;
                *(float4*)(&As[r][c4 * 4]) = *(const float4*)(A + (size_t)(m0 + r) * 128 + kc * 64 + c4 * 4);
                *(float4*)(&Bs[r][c4 * 4]) = *(const float4*)(Bm + (size_t)(kc * 64 + r) * 128 + n0 + c4 * 4);
            }
            __syncthreads();
#pragma unroll
            for (int k4 = 0; k4 < 16; k4++) {
                float4 a[4];
#pragma unroll
                for (int i = 0; i < 4; i++) a[i] = *(const float4*)(&As[ty * 4 + i][k4 * 4]);
#pragma unroll
                for (int kk = 0; kk < 4; kk++) {
                    float4 bv = *(const float4*)(&Bs[k4 * 4 + kk][tx * 4]);
#pragma unroll
                    for (int i = 0; i < 4; i++) {
                        float av = (kk == 0) ? a[i].x : (kk == 1) ? a[i].y : (kk == 2) ? a[i].z : a[i].w;
                        acc[i][0] += av * bv.x;
                        acc[i][1] += av * bv.y;
                        acc[i][2] += av * bv.z;
                        acc[i][3] += av * bv.w;
                    }
                }
            }
        }
    }
    if (cfg == 0) {
#pragma unroll
        for (int i = 0; i < 4; i++) {
            int m = m0 + ty * 4 + i;
            int n = n0 + tx * 4;
            *(float4*)(hp_t + (size_t)m * 128 + n) =
                make_float4(acc[i][0], acc[i][1], acc[i][2], acc[i][3]);
        }
    } else {
        __syncthreads();
#pragma unroll
        for (int i = 0; i < 4; i++)
#pragma unroll
            for (int j = 0; j < 4; j++)
                As[ty * 4 + i][tx * 4 + j] = tanh_fast(acc[i][j] + bs[n0 + tx * 4 + j]);
        __syncthreads();
        int b = m0 >> 9;
        int s0 = m0 & 511;
        int lane = tid & 63, wv = tid >> 6;
#pragma unroll 4
        for (int it = 0; it < 16; ++it) {
            int nl = wv * 16 + it;
            tc_sT[((size_t)(b * 128 + n0 + nl)) * 512 + s0 + lane] = As[lane][nl];
        }
    }
}

// ---------------------------------------------------------------------------
// LSTM core (proven R15/R18 state).
// ---------------------------------------------------------------------------
#define MF0(ACC, A, B) \
    asm("v_mfma_f32_16x16x32_f16 %0, %1, %2, %3" : "=&v"(ACC) : "v"(A), "a"(B), "v"(zro));
#define MF(ACC, A, B) \
    asm("v_mfma_f32_16x16x32_f16 %0, %1, %2, %0" : "+v"(ACC) : "v"(A), "a"(B));

#define LSTM_STEP(X0, X1, X2, X3, R0, R1, R2, R3, WPTR, PXG)                       \
    {                                                                              \
        f16x8 a0 = *(R0); f16x8 a1 = *(R1);                                        \
        f16x8 a2 = *(R2); f16x8 a3 = *(R3);                                        \
        float o0 = X0, o1 = X1, o2 = X2, o3 = X3;                                  \
        X0 = (PXG)[0]; X1 = (PXG)[128]; X2 = (PXG)[256]; X3 = (PXG)[384];          \
        (PXG) += 1024;                                                             \
        f32x4 ac0a, ac1a, ac2a, ac3a, ac0b, ac1b, ac2b, ac3b;                      \
        MF0(ac0a, a0, b00) MF0(ac1a, a0, b10) MF0(ac2a, a0, b20) MF0(ac3a, a0, b30)\
        MF0(ac0b, a2, b02) MF0(ac1b, a2, b12) MF0(ac2b, a2, b22) MF0(ac3b, a2, b32)\
        MF(ac0a, a1, b01) MF(ac1a, a1, b11) MF(ac2a, a1, b21) MF(ac3a, a1, b31)    \
        MF(ac0b, a3, b03) MF(ac1b, a3, b13) MF(ac2b, a3, b23) MF(ac3b, a3, b33)    \
        __builtin_amdgcn_sched_barrier(0);                                         \
        asm volatile("s_nop 7\n\ts_nop 7"                                          \
                     :: "v"(ac0a), "v"(ac1a), "v"(ac2a), "v"(ac3a),                \
                        "v"(ac0b), "v"(ac1b), "v"(ac2b), "v"(ac3b));               \
        __builtin_amdgcn_sched_barrier(0);                                         \
        float gi = ac0a[0] + ac0b[0] + o0;                                         \
        float gf = ac1a[0] + ac1b[0] + o1;                                         \
        float gg = ac2a[0] + ac2b[0] + o2;                                         \
        float go = ac3a[0] + ac3b[0] + o3;                                         \
        float si = sigmoid_fast(gi), sf = sigmoid_fast(gf), so = sigmoid_fast(go); \
        float tg = tanh_fast(gg);                                                  \
        c = sf * c + si * tg;                                                      \
        float h = so * tanh_fast(c);                                               \
        *(WPTR) = (_Float16)h;                                                     \
        *pH = h; pH += Hq;                                                         \
        __builtin_amdgcn_sched_barrier(0);                                         \
        asm volatile("s_waitcnt lgkmcnt(0)");                                      \
        __builtin_amdgcn_s_barrier();                                              \
        __builtin_amdgcn_sched_barrier(0);                                         \
    }

__device__ __forceinline__ void lstm_core(const float* __restrict__ xg,
                                          const _Float16* __restrict__ W16,
                                          float* __restrict__ Hout,
                                          _Float16* hbase, int tid) {
    int w = tid >> 6, lane = tid & 63;
    int r = lane & 15, kg = lane >> 4;   // kg = k-group AND batch id
    int ch = 16 * w + r;

    for (int i = tid; i < 4096; i += 512) hbase[i] = (_Float16)0.f;

    const _Float16* wb = W16 + (size_t)ch * 128 + kg * 8;
#define LWB(g, kb) *(const f16x8*)(wb + (size_t)(g) * 16384 + (kb) * 32)
    f16x8 b00 = LWB(0, 0), b01 = LWB(0, 1), b02 = LWB(0, 2), b03 = LWB(0, 3);
    f16x8 b10 = LWB(1, 0), b11 = LWB(1, 1), b12 = LWB(1, 2), b13 = LWB(1, 3);
    f16x8 b20 = LWB(2, 0), b21 = LWB(2, 1), b22 = LWB(2, 2), b23 = LWB(2, 3);
    f16x8 b30 = LWB(3, 0), b31 = LWB(3, 1), b32 = LWB(3, 2), b33 = LWB(3, 3);
#undef LWB
    f32x4 zro = {0.f, 0.f, 0.f, 0.f};
    asm volatile(""
                 : "+a"(b00), "+a"(b01), "+a"(b02), "+a"(b03),
                   "+a"(b10), "+a"(b11), "+a"(b12), "+a"(b13),
                   "+a"(b20), "+a"(b21), "+a"(b22), "+a"(b23),
                   "+a"(b30), "+a"(b31), "+a"(b32), "+a"(b33),
                   "+v"(zro));

    int aoff0 = r * 128 + (((0 * 4 + kg) ^ r) << 3);
    int aoff1 = r * 128 + (((1 * 4 + kg) ^ r) << 3);
    int aoff2 = r * 128 + (((2 * 4 + kg) ^ r) << 3);
    int aoff3 = r * 128 + (((3 * 4 + kg) ^ r) << 3);
    int woff = (4 * kg) * 128 + (((ch >> 3) ^ (4 * kg)) << 3) + (ch & 7);

    const f16x8* rA0 = (const f16x8*)(hbase + aoff0);
    const f16x8* rA1 = (const f16x8*)(hbase + aoff1);
    const f16x8* rA2 = (const f16x8*)(hbase + aoff2);
    const f16x8* rA3 = (const f16x8*)(hbase + aoff3);
    const f16x8* rB0 = (const f16x8*)(hbase + 2048 + aoff0);
    const f16x8* rB1 = (const f16x8*)(hbase + 2048 + aoff1);
    const f16x8* rB2 = (const f16x8*)(hbase + 2048 + aoff2);
    const f16x8* rB3 = (const f16x8*)(hbase + 2048 + aoff3);
    _Float16* wA = hbase + 2048 + woff;
    _Float16* wB = hbase + woff;

    size_t kgTq = (size_t)kg * Tq;
    const float* p0 = xg + (kgTq + 0) * 512 + ch;
    const float* p1 = xg + (kgTq + 1) * 512 + ch;
    float xa0 = p0[0], xa1 = p0[128], xa2 = p0[256], xa3 = p0[384];
    float xb0 = p1[0], xb1 = p1[128], xb2 = p1[256], xb3 = p1[384];
    const float* pA = xg + (kgTq + 2) * 512 + ch;
    const float* pB = xg + (kgTq + 3) * 512 + ch;
    float* pH = Hout + kgTq * Hq + ch;

    float c = 0.f;
    __syncthreads();

    for (int t = 0; t < Tq; t += 2) {
        LSTM_STEP(xa0, xa1, xa2, xa3, rA0, rA1, rA2, rA3, wA, pA)
        LSTM_STEP(xb0, xb1, xb2, xb3, rB0, rB1, rB2, rB3, wB, pB)
    }
}

// ---------------------------------------------------------------------------
// lstm_fused: block 0 = shared-LSTM recurrence; blocks 1..256 xg_t projection;
// blocks 257..320 Whh_t->f16 convert (all under the recurrence's shadow).
// ---------------------------------------------------------------------------
__global__ __launch_bounds__(512)
__attribute__((amdgpu_waves_per_eu(2, 2)))
void lstm_fused(const float* __restrict__ xg_s,
                const _Float16* __restrict__ W16_s,
                float* __restrict__ Hsh,
                const float* __restrict__ x,
                const float* __restrict__ Wih_t,
                const float* __restrict__ b_t,
                const float* __restrict__ Whh_t,
                float* __restrict__ xg_t,
                _Float16* __restrict__ W16_t) {
    __shared__ __align__(16) float smem[2][64][68];
    int bid = blockIdx.x;
    int tid = threadIdx.x;
    if (bid == 0) {
        lstm_core(xg_s, W16_s, Hsh, (_Float16*)&smem[0][0][0], tid);
    } else if (bid <= 256) {
        int b2 = bid - 1;
        gemm_nt_512(smem[0], smem[1], x, 128, Wih_t, 256, b_t, xg_t,
                    (b2 & 31) * 64, (b2 >> 5) * 64, tid);
    } else {
        int cb = bid - 257;                      // 0..63
        int i = (cb * 512 + tid) * 2;
        float2 v = *(const float2*)(Whh_t + i);
        W16_t[i] = (_Float16)v.x;
        W16_t[i + 1] = (_Float16)v.y;
    }
}

// ---------------------------------------------------------------------------
// lstm_b4 plain (task LSTM). grid 1, block 512.
// ---------------------------------------------------------------------------
__global__ __launch_bounds__(512)
__attribute__((amdgpu_waves_per_eu(2, 2)))
void lstm_b4(const float* __restrict__ xg,
             const _Float16* __restrict__ W16,
             float* __restrict__ Hout) {
    __shared__ _Float16 hbuf[2][16][128];
    lstm_core(xg, W16, Hout, &hbuf[0][0][0], threadIdx.x);
}

// ---------------------------------------------------------------------------
// Attention v8 (R18-proven): exact tanh addition identity, 1 rcp/elem.
// 4 t's per block, 512 blocks x 512 thr.
// ---------------------------------------------------------------------------
__global__ __launch_bounds__(512) void attn_kernel(const float* __restrict__ hp_t,
                                                   const float* __restrict__ tc_sT,
                                                   const float* __restrict__ u,
                                                   const float* __restrict__ Hsh,
                                                   float* __restrict__ R) {
    int t0 = blockIdx.x * 4;
    int b = blockIdx.y;
    int tid = threadIdx.x;
    int tq = tid >> 7, th = tid & 127;

    __shared__ __align__(16) float pa_lds[4][128];
    __shared__ __align__(16) float u_lds[128];
    __shared__ __align__(16) float sc[4][512];
    __shared__ __align__(16) float red[8];

    pa_lds[tq][th] = tanh_fast(hp_t[((size_t)b * Tq + t0 + tq) * Hq + th]);
    if (tid < 128) u_lds[tid] = u[tid];
    __syncthreads();

    const float* pc = tc_sT + (size_t)b * 65536 + 4 * th;   // [b][h][s]
    const float* pa = &pa_lds[tq][0];
    float acc0 = 0.f, acc1 = 0.f, acc2 = 0.f, acc3 = 0.f;
#pragma unroll 4
    for (int h = 0; h < 128; ++h) {
        float4 qv = *(const float4*)pc;
        float p = pa[h], uu = u_lds[h];
        float n0 = p + qv.x, n1 = p + qv.y, n2 = p + qv.z, n3 = p + qv.w;
        float d0 = fmaf(p, qv.x, 1.0f), d1 = fmaf(p, qv.y, 1.0f);
        float d2 = fmaf(p, qv.z, 1.0f), d3 = fmaf(p, qv.w, 1.0f);
        acc0 = fmaf(uu * n0, rcp_fast(d0), acc0);
        acc1 = fmaf(uu * n1, rcp_fast(d1), acc1);
        acc2 = fmaf(uu * n2, rcp_fast(d2), acc2);
        acc3 = fmaf(uu * n3, rcp_fast(d3), acc3);
        pc += 512;
    }
    float p0 = __expf(acc0), p1 = __expf(acc1);
    float p2 = __expf(acc2), p3 = __expf(acc3);
    *(float4*)&sc[tq][4 * th] = make_float4(p0, p1, p2, p3);

    float psum = p0 + p1 + p2 + p3;
#pragma unroll
    for (int off = 1; off < 64; off <<= 1) psum += __shfl_xor(psum, off, 64);
    int wv = tid >> 6;
    if ((tid & 63) == 0) red[wv] = psum;
    __syncthreads();
    float rinv = rcp_fast(red[2 * tq] + red[2 * tq + 1]);

    const float* hb = Hsh + (size_t)b * Tq * Hq + th;
    const float* scp = &sc[tq][0];
    float acc = 0.0f;
#pragma unroll 4
    for (int s = 0; s < 512; ++s) {
        acc = fmaf(scp[s], hb[(size_t)s * Hq], acc);
    }
    R[((size_t)b * Tq + t0 + tq) * Hq + th] = acc * rinv;
}

// ---------------------------------------------------------------------------
extern "C" void kernel_launch(void* const* d_in, const int* in_sizes, int n_in,
                              void* d_out, int out_size, void* d_ws, size_t ws_size,
                              hipStream_t stream) {
    const float* x      = (const float*)d_in[0];
    const float* Wih_s  = (const float*)d_in[1];
    const float* Whh_s  = (const float*)d_in[2];
    const float* b_s    = (const float*)d_in[3];
    const float* Wx     = (const float*)d_in[4];
    const float* Wht    = (const float*)d_in[5];
    const float* Whs    = (const float*)d_in[6];
    const float* bs     = (const float*)d_in[7];
    const float* u      = (const float*)d_in[8];
    // d_in[9] = bu: softmax-invariant, unused
    const float* Wih_t  = (const float*)d_in[10];
    const float* Whh_t  = (const float*)d_in[11];
    const float* b_t    = (const float*)d_in[12];
    float* out = (float*)d_out;

    // workspace layout (floats)
    float* ws    = (float*)d_ws;
    float* xg_s  = ws;                 // [B,T,512]
    float* xg_t  = ws + 1048576;       // [B,T,512]
    float* Hsh   = ws + 2097152;       // [B,T,128]
    float* hp_t  = ws + 2359296;       // [B,T,128] (W16_s home until mid writes)
    float* tc_sT = ws + 2621440;       // [B,128,512] tanh'd + transposed
    float* Rbuf  = ws + 2883584;       // [B,T,128]
    _Float16* W16_t = (_Float16*)(ws + 3145728);   // tail, survives to lstm2
    _Float16* W16_s = (_Float16*)hp_t;             // consumed by lstm1 before mid

    dim3 blk(256);

    // 1) prep: xg_s projection + W16_s convert (critical path to lstm1)
    prep<<<320, blk, 0, stream>>>(x, Wih_s, b_s, Whh_s, xg_s, W16_s);

    // 2) shared LSTM (block 0) + xg_t projection + W16_t convert (shadow)
    lstm_fused<<<321, 512, 0, stream>>>(xg_s, W16_s, Hsh,
                                        x, Wih_t, b_t, Whh_t, xg_t, W16_t);

    // 3) attention precursors: hp_t ; tc_sT = tanh(c_s)^T
    mid<<<128, blk, 0, stream>>>(x, Hsh, Wht, Wx, Whs, bs, hp_t, tc_sT);

    // 4) attention v8 (tanh addition identity, 1 rcp/elem)
    attn_kernel<<<dim3(Tq / 4, Bq), 512, 0, stream>>>(hp_t, tc_sT, u, Hsh, Rbuf);

    // 5) xg_t += R @ Wih_t[:,128:].T
    gemm_nt<<<dim3(32, 8), blk, 0, stream>>>(Rbuf, 128, Wih_t + 128, 256, nullptr, xg_t, 1);

    // 6) task LSTM -> output
    lstm_b4<<<1, 512, 0, stream>>>(xg_t, W16_t, out);
}